// Round 1
// baseline (228.746 us; speedup 1.0000x reference)
//
#include <hip/hip_runtime.h>
#include <hip/hip_bf16.h>

#define IN_DIMX 135909
#define OUT_DIMX 670091
#define DDIM 128
#define BATCH 256
#define TFEAT 100

typedef __bf16 bf16_t;
typedef __attribute__((ext_vector_type(8))) __bf16 bf16x8;
typedef __attribute__((ext_vector_type(4))) float f32x4;

// ---------------- K1: embedding bag sum -> L2 normalize -> +bias -> relu ----
__global__ void k_query(const int* __restrict__ x, const float* __restrict__ emb,
                        const float* __restrict__ bias, float* __restrict__ qf,
                        bf16_t* __restrict__ qb) {
    const int row = blockIdx.x;
    const int t = threadIdx.x; // 128 threads, one per dim
    __shared__ int sidx[TFEAT];
    if (t < TFEAT) sidx[t] = x[row * TFEAT + t];
    __syncthreads();
    float s = 0.f;
    #pragma unroll 10
    for (int i = 0; i < TFEAT; ++i) {
        s += emb[(size_t)sidx[i] * DDIM + t];
    }
    // block-wide sum of squares (128 threads = 2 waves)
    float sq = s * s;
    #pragma unroll
    for (int off = 1; off < 64; off <<= 1) sq += __shfl_xor(sq, off, 64);
    __shared__ float wred[2];
    if ((threadIdx.x & 63) == 0) wred[threadIdx.x >> 6] = sq;
    __syncthreads();
    const float tot = wred[0] + wred[1];
    float q = s / sqrtf(tot) + bias[t];
    q = fmaxf(q, 0.f);
    qf[row * DDIM + t] = q;
    qb[row * DDIM + t] = (bf16_t)q;
}

// ---------------- K2: MFMA logits + per-block partial sum-of-exp ------------
// Block = 256 threads = 4 waves. Wave w owns batch rows [w*64, w*64+64).
// Grid-stride over 64-class chunks. Per chunk: 4x4 tiles of 16x16x32 MFMA
// over K=128 (4 k-steps). Running per-lane sumexp, one shuffle-reduce at end.
__global__ __launch_bounds__(256, 2)
void k_lse(const float* __restrict__ W, const float* __restrict__ b_out,
           const bf16_t* __restrict__ qb, float* __restrict__ partials,
           int nblk) {
    const int lane = threadIdx.x & 63;
    const int w = threadIdx.x >> 6;
    const int l15 = lane & 15;
    const int l4 = lane >> 4;

    // A fragments: query rows for this wave's 64-batch slice (constant all kernel)
    bf16x8 a[4][4];
    #pragma unroll
    for (int mt = 0; mt < 4; ++mt)
        #pragma unroll
        for (int ks = 0; ks < 4; ++ks)
            a[mt][ks] = *(const bf16x8*)(qb + (w * 64 + mt * 16 + l15) * DDIM + ks * 32 + 8 * l4);

    float rs[4][4];
    #pragma unroll
    for (int mt = 0; mt < 4; ++mt)
        #pragma unroll
        for (int r = 0; r < 4; ++r) rs[mt][r] = 0.f;

    const int nchunks = (OUT_DIMX + 63) / 64;
    for (int ch = blockIdx.x; ch < nchunks; ch += nblk) {
        const int cbase = ch * 64;
        f32x4 acc[4][4];
        #pragma unroll
        for (int mt = 0; mt < 4; ++mt)
            #pragma unroll
            for (int nt = 0; nt < 4; ++nt) acc[mt][nt] = (f32x4){0.f, 0.f, 0.f, 0.f};

        #pragma unroll
        for (int ks = 0; ks < 4; ++ks) {
            bf16x8 b[4];
            #pragma unroll
            for (int nt = 0; nt < 4; ++nt) {
                const int rowc = cbase + nt * 16 + l15;
                f32x4 lo = (f32x4){0.f, 0.f, 0.f, 0.f};
                f32x4 hi = (f32x4){0.f, 0.f, 0.f, 0.f};
                if (rowc < OUT_DIMX) {
                    const float* p = W + (size_t)rowc * DDIM + ks * 32 + 8 * l4;
                    lo = *(const f32x4*)p;
                    hi = *(const f32x4*)(p + 4);
                }
                bf16x8 bb;
                bb[0] = (bf16_t)lo[0]; bb[1] = (bf16_t)lo[1];
                bb[2] = (bf16_t)lo[2]; bb[3] = (bf16_t)lo[3];
                bb[4] = (bf16_t)hi[0]; bb[5] = (bf16_t)hi[1];
                bb[6] = (bf16_t)hi[2]; bb[7] = (bf16_t)hi[3];
                b[nt] = bb;
            }
            #pragma unroll
            for (int nt = 0; nt < 4; ++nt)
                #pragma unroll
                for (int mt = 0; mt < 4; ++mt)
                    acc[mt][nt] = __builtin_amdgcn_mfma_f32_16x16x32_bf16(
                        a[mt][ks], b[nt], acc[mt][nt], 0, 0, 0);
        }

        // consume: logits -> running sum of exp
        #pragma unroll
        for (int nt = 0; nt < 4; ++nt) {
            const int col = cbase + nt * 16 + l15;
            const bool valid = (col < OUT_DIMX);
            const float bo = valid ? b_out[col] : 0.f;
            #pragma unroll
            for (int mt = 0; mt < 4; ++mt)
                #pragma unroll
                for (int r = 0; r < 4; ++r) {
                    const float v = acc[mt][nt][r] + bo;
                    rs[mt][r] += valid ? __expf(v) : 0.f;
                }
        }
    }

    // reduce across the 16 lanes (l15) sharing each output row, write partials
    #pragma unroll
    for (int mt = 0; mt < 4; ++mt)
        #pragma unroll
        for (int r = 0; r < 4; ++r) {
            float v = rs[mt][r];
            v += __shfl_xor(v, 1, 64);
            v += __shfl_xor(v, 2, 64);
            v += __shfl_xor(v, 4, 64);
            v += __shfl_xor(v, 8, 64);
            if (l15 == 0) {
                const int rowb = w * 64 + mt * 16 + l4 * 4 + r;
                partials[(size_t)blockIdx.x * BATCH + rowb] = v;
            }
        }
}

// ---------------- K3: logit at the label: dot(q_i, W[y_i]) + b_out[y_i] -----
__global__ void k_ydot(const int* __restrict__ y, const float* __restrict__ qf,
                       const float* __restrict__ W, const float* __restrict__ b_out,
                       float* __restrict__ logity) {
    const int i = blockIdx.x;
    const int lane = threadIdx.x; // 64
    const int yi = y[i];
    const float* wrow = W + (size_t)yi * DDIM;
    const float* qrow = qf + i * DDIM;
    float s = qrow[lane] * wrow[lane] + qrow[lane + 64] * wrow[lane + 64];
    #pragma unroll
    for (int off = 1; off < 64; off <<= 1) s += __shfl_xor(s, off, 64);
    if (lane == 0) logity[i] = s + b_out[yi];
}

// ---------------- K4: reduce partials -> logsumexp -> mean loss -------------
__global__ void k_loss(const float* __restrict__ partials,
                       const float* __restrict__ logity,
                       float* __restrict__ out, int nblk) {
    const int i = threadIdx.x; // 256, one per batch row
    float s = 0.f;
    #pragma unroll 8
    for (int b = 0; b < nblk; ++b) s += partials[(size_t)b * BATCH + i];
    float t = logf(s) - logity[i];
    // block reduce (4 waves)
    #pragma unroll
    for (int off = 1; off < 64; off <<= 1) t += __shfl_xor(t, off, 64);
    __shared__ float wred[4];
    if ((threadIdx.x & 63) == 0) wred[threadIdx.x >> 6] = t;
    __syncthreads();
    if (threadIdx.x == 0)
        out[0] = (wred[0] + wred[1] + wred[2] + wred[3]) * (1.0f / (float)BATCH);
}

extern "C" void kernel_launch(void* const* d_in, const int* in_sizes, int n_in,
                              void* d_out, int out_size, void* d_ws, size_t ws_size,
                              hipStream_t stream) {
    const int*   x     = (const int*)d_in[0];
    const int*   y     = (const int*)d_in[1];
    // d_in[2] = freeze, d_in[3] = slide (unused: exact/full softmax path)
    const float* emb   = (const float*)d_in[4];
    const float* bias  = (const float*)d_in[5];
    const float* W     = (const float*)d_in[6];
    const float* b_out = (const float*)d_in[7];
    float* out = (float*)d_out;

    char* ws = (char*)d_ws;
    bf16_t* qb      = (bf16_t*)(ws);            // 256*128*2 = 64 KB
    float*  qf      = (float*)(ws + 65536);     // 256*128*4 = 128 KB
    float*  logity  = (float*)(ws + 196608);    // 1 KB
    float*  partials = (float*)(ws + 262144);   // nblk*256*4

    int nblk = 1024;
    size_t need = 262144 + (size_t)nblk * BATCH * 4;
    if (ws_size < need) {
        size_t avail = (ws_size > 262144) ? (ws_size - 262144) / (BATCH * 4) : 1;
        nblk = (int)(avail < 1 ? 1 : avail);
        if (nblk > 1024) nblk = 1024;
    }

    k_query<<<BATCH, DDIM, 0, stream>>>(x, emb, bias, qf, qb);
    k_ydot<<<BATCH, 64, 0, stream>>>(y, qf, W, b_out, logity);
    k_lse<<<nblk, 256, 0, stream>>>(W, b_out, qb, partials, nblk);
    k_loss<<<1, 256, 0, stream>>>(partials, logity, out, nblk);
}

// Round 2
// 134.866 us; speedup vs baseline: 1.6961x; 1.6961x over previous
//
#include <hip/hip_runtime.h>
#include <hip/hip_bf16.h>

#define IN_DIMX 135909
#define OUT_DIMX 670091
#define DDIM 128
#define BATCH 256
#define TFEAT 100
#define NBLK 512                      // k_lse grid: 2 blocks/CU, both resident
#define NCHUNK ((OUT_DIMX + 63) / 64) // 10471 chunks of 64 classes

typedef __bf16 bf16_t;
typedef __attribute__((ext_vector_type(8))) __bf16 bf16x8;
typedef __attribute__((ext_vector_type(4))) float f32x4;

__device__ __forceinline__ void load_lds16(const void* g, void* l) {
    __builtin_amdgcn_global_load_lds(
        (const __attribute__((address_space(1))) void*)g,
        (__attribute__((address_space(3))) void*)l, 16, 0, 0);
}

// ---------------- K1: embedding bag sum -> L2 normalize -> +bias -> relu ----
__global__ void k_query(const int* __restrict__ x, const float* __restrict__ emb,
                        const float* __restrict__ bias, float* __restrict__ qf,
                        bf16_t* __restrict__ qb) {
    const int row = blockIdx.x;
    const int t = threadIdx.x; // 128 threads, one per dim
    __shared__ int sidx[TFEAT];
    if (t < TFEAT) sidx[t] = x[row * TFEAT + t];
    __syncthreads();
    float s = 0.f;
    #pragma unroll 10
    for (int i = 0; i < TFEAT; ++i) {
        s += emb[(size_t)sidx[i] * DDIM + t];
    }
    float sq = s * s;
    #pragma unroll
    for (int off = 1; off < 64; off <<= 1) sq += __shfl_xor(sq, off, 64);
    __shared__ float wred[2];
    if ((threadIdx.x & 63) == 0) wred[threadIdx.x >> 6] = sq;
    __syncthreads();
    const float tot = wred[0] + wred[1];
    float q = s / sqrtf(tot) + bias[t];
    q = fmaxf(q, 0.f);
    qf[row * DDIM + t] = q;
    qb[row * DDIM + t] = (bf16_t)q;
}

// ---------------- K2: MFMA logits + per-block partial sum-of-exp ------------
// Block = 256 threads = 4 waves; wave w owns batch rows [64w, 64w+64).
// Grid-strides over 64-class chunks. W chunk (64x128 fp32 = 32 KB) staged
// into LDS once per block via global_load_lds, double-buffered, ONE barrier
// per chunk (stage(next) issued before compute(cur) so HBM latency hides
// under compute). LDS uses a 16B-slot XOR swizzle applied on the pre-swizzled
// GLOBAL source (global_load_lds dest must stay linear): LDS slot s holds
// W[s>>5][(s&31) ^ ((s>>5)&7)], so reading row r col-slot cb uses slot
// r*32 + (cb ^ (r&7)) -> uniform bank-quad spread for ds_read_b128.
__global__ __launch_bounds__(256, 2)
void k_lse(const float* __restrict__ W, const float* __restrict__ b_out,
           const bf16_t* __restrict__ qb, float* __restrict__ partials) {
    __shared__ float lds[2][64 * 128]; // 2 x 32 KB
    const int tid = threadIdx.x;
    const int lane = tid & 63;
    const int w = tid >> 6;
    const int l15 = lane & 15;
    const int l4 = lane >> 4;

    // A fragments: this wave's 64 batch rows (constant for whole kernel)
    bf16x8 a[4][4];
    #pragma unroll
    for (int mt = 0; mt < 4; ++mt)
        #pragma unroll
        for (int ks = 0; ks < 4; ++ks)
            a[mt][ks] = *(const bf16x8*)(qb + (w * 64 + mt * 16 + l15) * DDIM + ks * 32 + 8 * l4);

    float rs[4][4];
    #pragma unroll
    for (int mt = 0; mt < 4; ++mt)
        #pragma unroll
        for (int r = 0; r < 4; ++r) rs[mt][r] = 0.f;

    auto stage = [&](int buf, int ch) {
        const int cbase = ch * 64;
        #pragma unroll
        for (int rnd = 0; rnd < 8; ++rnd) {
            const int s = rnd * 256 + tid;  // 16B-slot index 0..2047
            const int r = s >> 5;           // chunk row 0..63
            const int sc = s & 31;          // dest col-slot
            const int scs = sc ^ (r & 7);   // swizzled SOURCE col-slot
            int gr = cbase + r;
            gr = gr < OUT_DIMX ? gr : OUT_DIMX - 1; // clamp tail: unconditional load
            load_lds16(W + (size_t)gr * DDIM + scs * 4, &lds[buf][s * 4]);
        }
    };

    int cur = 0;
    stage(0, blockIdx.x);
    for (int ch = blockIdx.x; ch < NCHUNK; ch += NBLK) {
        __syncthreads(); // drains vmcnt -> buf[cur] ready; prev compute done -> buf[cur^1] reusable
        const int nxt = ch + NBLK;
        if (nxt < NCHUNK) stage(cur ^ 1, nxt);

        const int cbase = ch * 64;
        f32x4 acc[4][4];
        #pragma unroll
        for (int mt = 0; mt < 4; ++mt)
            #pragma unroll
            for (int nt = 0; nt < 4; ++nt) acc[mt][nt] = (f32x4){0.f, 0.f, 0.f, 0.f};

        #pragma unroll
        for (int ks = 0; ks < 4; ++ks) {
            bf16x8 b[4];
            #pragma unroll
            for (int nt = 0; nt < 4; ++nt) {
                const int row = nt * 16 + l15;
                const int cb = 8 * ks + 2 * l4;
                const int r7 = row & 7;
                const f32x4 lo = *(const f32x4*)&lds[cur][(row * 32 + (cb ^ r7)) * 4];
                const f32x4 hi = *(const f32x4*)&lds[cur][(row * 32 + ((cb + 1) ^ r7)) * 4];
                bf16x8 bb;
                bb[0] = (bf16_t)lo[0]; bb[1] = (bf16_t)lo[1];
                bb[2] = (bf16_t)lo[2]; bb[3] = (bf16_t)lo[3];
                bb[4] = (bf16_t)hi[0]; bb[5] = (bf16_t)hi[1];
                bb[6] = (bf16_t)hi[2]; bb[7] = (bf16_t)hi[3];
                b[nt] = bb;
            }
            #pragma unroll
            for (int nt = 0; nt < 4; ++nt)
                #pragma unroll
                for (int mt = 0; mt < 4; ++mt)
                    acc[mt][nt] = __builtin_amdgcn_mfma_f32_16x16x32_bf16(
                        a[mt][ks], b[nt], acc[mt][nt], 0, 0, 0);
        }

        #pragma unroll
        for (int nt = 0; nt < 4; ++nt) {
            const int col = cbase + nt * 16 + l15;
            const bool valid = (col < OUT_DIMX);
            const float bo = b_out[valid ? col : OUT_DIMX - 1];
            #pragma unroll
            for (int mt = 0; mt < 4; ++mt)
                #pragma unroll
                for (int r = 0; r < 4; ++r) {
                    const float v = acc[mt][nt][r] + bo;
                    rs[mt][r] += valid ? __expf(v) : 0.f;
                }
        }
        cur ^= 1;
    }

    // reduce across the 16 lanes sharing each batch row; transposed layout
    // partials[row * NBLK + blk] so k_rowlse reads coalesced.
    #pragma unroll
    for (int mt = 0; mt < 4; ++mt)
        #pragma unroll
        for (int r = 0; r < 4; ++r) {
            float v = rs[mt][r];
            v += __shfl_xor(v, 1, 64);
            v += __shfl_xor(v, 2, 64);
            v += __shfl_xor(v, 4, 64);
            v += __shfl_xor(v, 8, 64);
            if (l15 == 0) {
                const int rowb = w * 64 + mt * 16 + l4 * 4 + r;
                partials[(size_t)rowb * NBLK + blockIdx.x] = v;
            }
        }
}

// ---------------- K3: logit at the label: dot(q_i, W[y_i]) + b_out[y_i] -----
__global__ void k_ydot(const int* __restrict__ y, const float* __restrict__ qf,
                       const float* __restrict__ W, const float* __restrict__ b_out,
                       float* __restrict__ logity) {
    const int i = blockIdx.x;
    const int lane = threadIdx.x; // 64
    const int yi = y[i];
    const float* wrow = W + (size_t)yi * DDIM;
    const float* qrow = qf + i * DDIM;
    float s = qrow[lane] * wrow[lane] + qrow[lane + 64] * wrow[lane + 64];
    #pragma unroll
    for (int off = 1; off < 64; off <<= 1) s += __shfl_xor(s, off, 64);
    if (lane == 0) logity[i] = s + b_out[yi];
}

// ---------------- K4a: per-row logsumexp from partials (coalesced) ----------
__global__ void k_rowlse(const float* __restrict__ partials,
                         const float* __restrict__ logity,
                         float* __restrict__ rowloss) {
    const int i = blockIdx.x;     // batch row
    const int lane = threadIdx.x; // 64
    float s = 0.f;
    #pragma unroll
    for (int k = 0; k < NBLK / 64; ++k)
        s += partials[(size_t)i * NBLK + k * 64 + lane];
    #pragma unroll
    for (int off = 1; off < 64; off <<= 1) s += __shfl_xor(s, off, 64);
    if (lane == 0) rowloss[i] = logf(s) - logity[i];
}

// ---------------- K4b: mean over batch -> scalar loss -----------------------
__global__ void k_final(const float* __restrict__ rowloss, float* __restrict__ out) {
    const int i = threadIdx.x; // 256
    float t = rowloss[i];
    #pragma unroll
    for (int off = 1; off < 64; off <<= 1) t += __shfl_xor(t, off, 64);
    __shared__ float wred[4];
    if ((threadIdx.x & 63) == 0) wred[threadIdx.x >> 6] = t;
    __syncthreads();
    if (threadIdx.x == 0)
        out[0] = (wred[0] + wred[1] + wred[2] + wred[3]) * (1.0f / (float)BATCH);
}

extern "C" void kernel_launch(void* const* d_in, const int* in_sizes, int n_in,
                              void* d_out, int out_size, void* d_ws, size_t ws_size,
                              hipStream_t stream) {
    const int*   x     = (const int*)d_in[0];
    const int*   y     = (const int*)d_in[1];
    // d_in[2] = freeze, d_in[3] = slide (unused: exact/full softmax path)
    const float* emb   = (const float*)d_in[4];
    const float* bias  = (const float*)d_in[5];
    const float* W     = (const float*)d_in[6];
    const float* b_out = (const float*)d_in[7];
    float* out = (float*)d_out;

    char* ws = (char*)d_ws;
    bf16_t* qb       = (bf16_t*)(ws);           // 256*128*2 = 64 KB
    float*  qf       = (float*)(ws + 65536);    // 256*128*4 = 128 KB
    float*  logity   = (float*)(ws + 196608);   // 1 KB
    float*  rowloss  = (float*)(ws + 197632);   // 1 KB
    float*  partials = (float*)(ws + 262144);   // 256*NBLK*4 = 512 KB

    k_query<<<BATCH, DDIM, 0, stream>>>(x, emb, bias, qf, qb);
    k_ydot<<<BATCH, 64, 0, stream>>>(y, qf, W, b_out, logity);
    k_lse<<<NBLK, 256, 0, stream>>>(W, b_out, qb, partials);
    k_rowlse<<<BATCH, 64, 0, stream>>>(partials, logity, rowloss);
    k_final<<<1, 256, 0, stream>>>(rowloss, out);
}

// Round 3
// 90.653 us; speedup vs baseline: 2.5233x; 1.4877x over previous
//
#include <hip/hip_runtime.h>
#include <hip/hip_bf16.h>

#define IN_DIMX 135909
#define OUT_DIMX 670091
#define DDIM 128
#define BATCH 256
#define TFEAT 100
#define NBLK 512                      // k_lse grid: 2 blocks/CU resident (VGPR-capped)
#define NCHUNK ((OUT_DIMX + 63) / 64) // 10471 chunks of 64 classes

typedef __bf16 bf16_t;
typedef __attribute__((ext_vector_type(8))) __bf16 bf16x8;
typedef __attribute__((ext_vector_type(4))) __bf16 bf16x4;
typedef __attribute__((ext_vector_type(4))) float f32x4;

// ---------------- K1: embedding bag sum -> L2 normalize -> +bias -> relu ----
__global__ void k_query(const int* __restrict__ x, const float* __restrict__ emb,
                        const float* __restrict__ bias, float* __restrict__ qf,
                        bf16_t* __restrict__ qb) {
    const int row = blockIdx.x;
    const int t = threadIdx.x; // 128 threads, one per dim
    __shared__ int sidx[TFEAT];
    if (t < TFEAT) sidx[t] = x[row * TFEAT + t];
    __syncthreads();
    float s = 0.f;
    #pragma unroll 10
    for (int i = 0; i < TFEAT; ++i) {
        s += emb[(size_t)sidx[i] * DDIM + t];
    }
    float sq = s * s;
    #pragma unroll
    for (int off = 1; off < 64; off <<= 1) sq += __shfl_xor(sq, off, 64);
    __shared__ float wred[2];
    if ((threadIdx.x & 63) == 0) wred[threadIdx.x >> 6] = sq;
    __syncthreads();
    const float tot = wred[0] + wred[1];
    float q = s / sqrtf(tot) + bias[t];
    q = fmaxf(q, 0.f);
    qf[row * DDIM + t] = q;
    qb[row * DDIM + t] = (bf16_t)q;
}

// ---------------- K2: MFMA logits + per-block partial sum-of-exp ------------
// Block = 256 threads = 4 waves; wave w owns batch rows [64w, 64w+64).
// Per 64-class chunk: W staged global->regs (coalesced dwordx4), converted to
// bf16 in-reg, ds_write_b64 into a 2x16KB bf16 double buffer with a 16B-slot
// XOR swizzle (slot_phys = row*16 + (c16 ^ (row&7))) -> conflict-free
// ds_read_b128 fragments, zero converts in the hot path. Barrier placed where
// NO global load is outstanding (drain-free); next chunk's loads issued right
// after the barrier so they fly across the whole compute phase.
__global__ __launch_bounds__(256, 2)
void k_lse(const float* __restrict__ W, const float* __restrict__ b_out,
           const bf16_t* __restrict__ qb, float* __restrict__ partials) {
    __shared__ bf16_t lds[2][64 * DDIM]; // 2 x 16 KB bf16
    const int tid = threadIdx.x;
    const int lane = tid & 63;
    const int w = tid >> 6;
    const int l15 = lane & 15;
    const int l4 = lane >> 4;

    // A fragments: this wave's 64 batch rows (constant for whole kernel)
    bf16x8 a[4][4];
    #pragma unroll
    for (int mt = 0; mt < 4; ++mt)
        #pragma unroll
        for (int ks = 0; ks < 4; ++ks)
            a[mt][ks] = *(const bf16x8*)(qb + (w * 64 + mt * 16 + l15) * DDIM + ks * 32 + 8 * l4);

    float rs[4][4];
    #pragma unroll
    for (int mt = 0; mt < 4; ++mt)
        #pragma unroll
        for (int r = 0; r < 4; ++r) rs[mt][r] = 0.f;

    // staging geometry: thread covers f32 elements (row = j*8 + tid>>5,
    // cols [(tid&31)*4, +4)) of the 64x128 chunk; global access per load j is
    // a flat contiguous 1KB/wave segment.
    const int srow = tid >> 5;
    const int scol = (tid & 31) * 4;
    const int c16  = (tid & 31) >> 1;  // dest 16B slot within row
    const int half = (tid & 1) * 4;    // bf16 offset within slot

    f32x4 wr[8];
    float bo_n[4];

    auto issue = [&](int ch) {
        const int cb = ch * 64;
        #pragma unroll
        for (int j = 0; j < 8; ++j) {
            int r = cb + j * 8 + srow;
            r = (r < OUT_DIMX) ? r : 0; // clamp: unconditional, in-bounds
            wr[j] = *(const f32x4*)(W + (size_t)r * DDIM + scol);
        }
        #pragma unroll
        for (int nt = 0; nt < 4; ++nt) {
            int c = cb + nt * 16 + l15;
            c = (c < OUT_DIMX) ? c : 0;
            bo_n[nt] = b_out[c];
        }
    };

    auto convwrite = [&](int cur) {
        #pragma unroll
        for (int j = 0; j < 8; ++j) {
            const int row = j * 8 + srow;
            const int sp = row * 16 + (c16 ^ (row & 7));
            bf16x4 v;
            v[0] = (bf16_t)wr[j][0]; v[1] = (bf16_t)wr[j][1];
            v[2] = (bf16_t)wr[j][2]; v[3] = (bf16_t)wr[j][3];
            *(bf16x4*)(&lds[cur][sp * 8 + half]) = v;
        }
    };

    int cur = 0;
    issue(blockIdx.x);
    for (int ch = blockIdx.x; ch < NCHUNK; ch += NBLK) {
        float bo_c[4];
        #pragma unroll
        for (int nt = 0; nt < 4; ++nt) bo_c[nt] = bo_n[nt];

        convwrite(cur);          // waits wr's vmcnt incrementally
        __syncthreads();         // nothing in flight -> drain-free barrier
        __builtin_amdgcn_sched_barrier(0);
        if (ch + NBLK < NCHUNK) issue(ch + NBLK); // flies across compute

        f32x4 acc[4][4];
        #pragma unroll
        for (int mt = 0; mt < 4; ++mt)
            #pragma unroll
            for (int nt = 0; nt < 4; ++nt) acc[mt][nt] = (f32x4){0.f, 0.f, 0.f, 0.f};

        #pragma unroll
        for (int ks = 0; ks < 4; ++ks) {
            bf16x8 b[4];
            #pragma unroll
            for (int nt = 0; nt < 4; ++nt) {
                const int row = nt * 16 + l15;
                const int sp = row * 16 + ((ks * 4 + l4) ^ (row & 7));
                b[nt] = *(const bf16x8*)(&lds[cur][sp * 8]);
            }
            #pragma unroll
            for (int nt = 0; nt < 4; ++nt)
                #pragma unroll
                for (int mt = 0; mt < 4; ++mt)
                    acc[mt][nt] = __builtin_amdgcn_mfma_f32_16x16x32_bf16(
                        a[mt][ks], b[nt], acc[mt][nt], 0, 0, 0);
        }

        const int cbase = ch * 64;
        if (cbase + 64 <= OUT_DIMX) { // full chunk: no masking
            #pragma unroll
            for (int nt = 0; nt < 4; ++nt)
                #pragma unroll
                for (int mt = 0; mt < 4; ++mt)
                    #pragma unroll
                    for (int r = 0; r < 4; ++r)
                        rs[mt][r] += __expf(acc[mt][nt][r] + bo_c[nt]);
        } else { // single partial tail chunk
            #pragma unroll
            for (int nt = 0; nt < 4; ++nt) {
                const bool valid = (cbase + nt * 16 + l15 < OUT_DIMX);
                #pragma unroll
                for (int mt = 0; mt < 4; ++mt)
                    #pragma unroll
                    for (int r = 0; r < 4; ++r)
                        rs[mt][r] += valid ? __expf(acc[mt][nt][r] + bo_c[nt]) : 0.f;
            }
        }
        cur ^= 1;
    }

    // reduce across the 16 lanes sharing each batch row; transposed layout
    // partials[row * NBLK + blk] so k_rowlse reads coalesced.
    #pragma unroll
    for (int mt = 0; mt < 4; ++mt)
        #pragma unroll
        for (int r = 0; r < 4; ++r) {
            float v = rs[mt][r];
            v += __shfl_xor(v, 1, 64);
            v += __shfl_xor(v, 2, 64);
            v += __shfl_xor(v, 4, 64);
            v += __shfl_xor(v, 8, 64);
            if (l15 == 0) {
                const int rowb = w * 64 + mt * 16 + l4 * 4 + r;
                partials[(size_t)rowb * NBLK + blockIdx.x] = v;
            }
        }
}

// ---------------- K3: logit at the label: dot(q_i, W[y_i]) + b_out[y_i] -----
__global__ void k_ydot(const int* __restrict__ y, const float* __restrict__ qf,
                       const float* __restrict__ W, const float* __restrict__ b_out,
                       float* __restrict__ logity) {
    const int i = blockIdx.x;
    const int lane = threadIdx.x; // 64
    const int yi = y[i];
    const float* wrow = W + (size_t)yi * DDIM;
    const float* qrow = qf + i * DDIM;
    float s = qrow[lane] * wrow[lane] + qrow[lane + 64] * wrow[lane + 64];
    #pragma unroll
    for (int off = 1; off < 64; off <<= 1) s += __shfl_xor(s, off, 64);
    if (lane == 0) logity[i] = s + b_out[yi];
}

// ---------------- K4a: per-row logsumexp from partials (coalesced) ----------
__global__ void k_rowlse(const float* __restrict__ partials,
                         const float* __restrict__ logity,
                         float* __restrict__ rowloss) {
    const int i = blockIdx.x;     // batch row
    const int lane = threadIdx.x; // 64
    float s = 0.f;
    #pragma unroll
    for (int k = 0; k < NBLK / 64; ++k)
        s += partials[(size_t)i * NBLK + k * 64 + lane];
    #pragma unroll
    for (int off = 1; off < 64; off <<= 1) s += __shfl_xor(s, off, 64);
    if (lane == 0) rowloss[i] = logf(s) - logity[i];
}

// ---------------- K4b: mean over batch -> scalar loss -----------------------
__global__ void k_final(const float* __restrict__ rowloss, float* __restrict__ out) {
    const int i = threadIdx.x; // 256
    float t = rowloss[i];
    #pragma unroll
    for (int off = 1; off < 64; off <<= 1) t += __shfl_xor(t, off, 64);
    __shared__ float wred[4];
    if ((threadIdx.x & 63) == 0) wred[threadIdx.x >> 6] = t;
    __syncthreads();
    if (threadIdx.x == 0)
        out[0] = (wred[0] + wred[1] + wred[2] + wred[3]) * (1.0f / (float)BATCH);
}

extern "C" void kernel_launch(void* const* d_in, const int* in_sizes, int n_in,
                              void* d_out, int out_size, void* d_ws, size_t ws_size,
                              hipStream_t stream) {
    const int*   x     = (const int*)d_in[0];
    const int*   y     = (const int*)d_in[1];
    // d_in[2] = freeze, d_in[3] = slide (unused: exact/full softmax path)
    const float* emb   = (const float*)d_in[4];
    const float* bias  = (const float*)d_in[5];
    const float* W     = (const float*)d_in[6];
    const float* b_out = (const float*)d_in[7];
    float* out = (float*)d_out;

    char* ws = (char*)d_ws;
    bf16_t* qb       = (bf16_t*)(ws);           // 256*128*2 = 64 KB
    float*  qf       = (float*)(ws + 65536);    // 256*128*4 = 128 KB
    float*  logity   = (float*)(ws + 196608);   // 1 KB
    float*  rowloss  = (float*)(ws + 197632);   // 1 KB
    float*  partials = (float*)(ws + 262144);   // 256*NBLK*4 = 512 KB

    k_query<<<BATCH, DDIM, 0, stream>>>(x, emb, bias, qf, qb);
    k_ydot<<<BATCH, 64, 0, stream>>>(y, qf, W, b_out, logity);
    k_lse<<<NBLK, 256, 0, stream>>>(W, b_out, qb, partials);
    k_rowlse<<<BATCH, 64, 0, stream>>>(partials, logity, rowloss);
    k_final<<<1, 256, 0, stream>>>(rowloss, out);
}